// Round 11
// baseline (584.497 us; speedup 1.0000x reference)
//
#include <hip/hip_runtime.h>

#define BN 64
#define CN 32
#define HEADSN 8
#define HDN 4
#define LN 6400
#define CL (CN*LN)   // 204800

// ---------- helpers ----------

__device__ __forceinline__ unsigned fenc(float f){
  unsigned u = __float_as_uint(f);
  return (u & 0x80000000u) ? ~u : (u | 0x80000000u);
}
__device__ __forceinline__ float fdec(unsigned u){
  unsigned v = (u & 0x80000000u) ? (u & 0x7FFFFFFFu) : ~u;
  return __uint_as_float(v);
}

// pack two f32 -> 2x bf16 (RNE) in one u32 ; unpack back to two f32
__device__ __forceinline__ unsigned pk_bf16(float a, float b){
  unsigned ua = __float_as_uint(a), ub = __float_as_uint(b);
  ua = (ua + 0x7fffu + ((ua >> 16) & 1u)) >> 16;
  ub = (ub + 0x7fffu + ((ub >> 16) & 1u)) >> 16;
  return ua | (ub << 16);
}
__device__ __forceinline__ float2 upk_bf16(unsigned u){
  return make_float2(__uint_as_float(u << 16), __uint_as_float(u & 0xffff0000u));
}

// Butterfly-reduce 32 per-thread values across the 64 lanes of a wave.
template<bool MAXOP>
__device__ __forceinline__ float bfly32(const float* in, int lane, int* chOut){
  const bool h0 = (lane & 1)  != 0, h1 = (lane & 2)  != 0, h2 = (lane & 4) != 0,
             h3 = (lane & 8)  != 0, h4 = (lane & 16) != 0;
  float a[16];
  #pragma unroll
  for (int i = 0; i < 16; ++i){
    float send = h0 ? in[i] : in[i+16];
    float keep = h0 ? in[i+16] : in[i];
    float recv = __shfl_xor(send, 1, 64);
    a[i] = MAXOP ? fmaxf(keep, recv) : keep + recv;
  }
  float b[8];
  #pragma unroll
  for (int i = 0; i < 8; ++i){
    float send = h1 ? a[i] : a[i+8];
    float keep = h1 ? a[i+8] : a[i];
    float recv = __shfl_xor(send, 2, 64);
    b[i] = MAXOP ? fmaxf(keep, recv) : keep + recv;
  }
  float c[4];
  #pragma unroll
  for (int i = 0; i < 4; ++i){
    float send = h2 ? b[i] : b[i+4];
    float keep = h2 ? b[i+4] : b[i];
    float recv = __shfl_xor(send, 4, 64);
    c[i] = MAXOP ? fmaxf(keep, recv) : keep + recv;
  }
  float d[2];
  #pragma unroll
  for (int i = 0; i < 2; ++i){
    float send = h3 ? c[i] : c[i+2];
    float keep = h3 ? c[i+2] : c[i];
    float recv = __shfl_xor(send, 8, 64);
    d[i] = MAXOP ? fmaxf(keep, recv) : keep + recv;
  }
  float e;
  {
    float send = h4 ? d[0] : d[1];
    float keep = h4 ? d[1] : d[0];
    float recv = __shfl_xor(send, 16, 64);
    e = MAXOP ? fmaxf(keep, recv) : keep + recv;
  }
  {
    float recv = __shfl_xor(e, 32, 64);
    e = MAXOP ? fmaxf(e, recv) : e + recv;
  }
  *chOut = (h0?16:0)|(h1?8:0)|(h2?4:0)|(h3?2:0)|(h4?1:0);
  return e;
}

__device__ __forceinline__ float bfly16_sum(const float* in, int lane, int* chOut){
  const bool h0 = (lane & 1) != 0, h1 = (lane & 2) != 0, h2 = (lane & 4) != 0,
             h3 = (lane & 8) != 0;
  float a[8];
  #pragma unroll
  for (int i = 0; i < 8; ++i){
    float send = h0 ? in[i] : in[i+8];
    float keep = h0 ? in[i+8] : in[i];
    float recv = __shfl_xor(send, 1, 64);
    a[i] = keep + recv;
  }
  float b[4];
  #pragma unroll
  for (int i = 0; i < 4; ++i){
    float send = h1 ? a[i] : a[i+4];
    float keep = h1 ? a[i+4] : a[i];
    float recv = __shfl_xor(send, 2, 64);
    b[i] = keep + recv;
  }
  float c[2];
  #pragma unroll
  for (int i = 0; i < 2; ++i){
    float send = h2 ? b[i] : b[i+2];
    float keep = h2 ? b[i+2] : b[i];
    float recv = __shfl_xor(send, 4, 64);
    c[i] = keep + recv;
  }
  float e;
  {
    float send = h3 ? c[0] : c[1];
    float keep = h3 ? c[1] : c[0];
    float recv = __shfl_xor(send, 8, 64);
    e = keep + recv;
  }
  e += __shfl_xor(e, 16, 64);
  e += __shfl_xor(e, 32, 64);
  *chOut = (h0?8:0)|(h1?4:0)|(h2?2:0)|(h3?1:0);
  return e;
}

// ---------- K1: merged LA+XCA reduce, 512-thread blocks (unchanged r7) ----------
__global__ __launch_bounds__(512) void k_reduce2(const float* __restrict__ rgb,
    const float* __restrict__ freq, const float* __restrict__ Wla,
    const float* __restrict__ Wxa, float* __restrict__ la_attn,
    float* __restrict__ xa_sums){
  __shared__ float2 xs2[2*128*17];     // 34.8 KB: two 128-px tiles
  const bool isXA = blockIdx.x >= 25;
  const int b = blockIdx.y, tid = threadIdx.x;
  const int half = tid >> 8;           // which tile
  const int wt = tid & 255;
  const int bxt = isXA ? (int)blockIdx.x - 25 : (int)blockIdx.x;
  const int l0 = (bxt*2 + half)*128;
  const float* xg = (isXA ? freq : rgb) + (size_t)b*CL + l0;
  float2* xs = xs2 + half*(128*17);
  // stage: 128 px x 16 channel-pairs per tile, 8 pairs per thread
  {
    const int px = wt & 127;
    const int c2b_ = (wt >> 7)*8;
    #pragma unroll
    for (int j = 0; j < 8; ++j){
      const int c2 = c2b_ + j;
      float e0 = xg[(2*c2)*LN + px];
      float e1 = xg[(2*c2+1)*LN + px];
      xs[px*17 + c2] = make_float2(e0, e1);
    }
  }
  __syncthreads();
  const int wave = __builtin_amdgcn_readfirstlane((tid >> 6) & 3);
  const int lane = tid & 63;
  if (!isXA){
    const float* Wk = Wla + (32 + wave*8)*32;
    const float* Wv = Wla + (64 + wave*8)*32;
    float acc[32];
    #pragma unroll
    for (int i = 0; i < 32; ++i) acc[i] = 0.f;
    for (int it = 0; it < 2; ++it){
      const int ll = it*64 + lane;
      float xv[32];
      #pragma unroll
      for (int c2 = 0; c2 < 16; ++c2){
        float2 t = xs[ll*17 + c2];
        xv[2*c2] = t.x; xv[2*c2+1] = t.y;
      }
      float kk[8], vv[8];
      #pragma unroll
      for (int r = 0; r < 8; ++r){ kk[r] = 0.f; vv[r] = 0.f; }
      #pragma unroll
      for (int c = 0; c < 32; ++c){
        #pragma unroll
        for (int r = 0; r < 8; ++r){
          kk[r] = fmaf(Wk[r*32 + c], xv[c], kk[r]);
          vv[r] = fmaf(Wv[r*32 + c], xv[c], vv[r]);
        }
      }
      #pragma unroll
      for (int hh = 0; hh < 2; ++hh){
        const float* k = kk + hh*4;
        const float* v = vv + hh*4;
        float rn = rsqrtf(k[0]*k[0] + k[1]*k[1] + k[2]*k[2] + k[3]*k[3]);
        #pragma unroll
        for (int d = 0; d < 4; ++d){
          float kn = k[d]*rn;
          #pragma unroll
          for (int e = 0; e < 4; ++e)
            acc[hh*16 + d*4 + e] = fmaf(kn, v[e], acc[hh*16 + d*4 + e]);
        }
      }
    }
    int ch;
    float s = bfly32<false>(acc, lane, &ch);
    if (lane < 32) atomicAdd(la_attn + b*128 + wave*32 + ch, s);
  } else {
    const float* Wq = Wxa + (0  + wave*8)*32;
    const float* Wk = Wxa + (32 + wave*8)*32;
    float acc[48];
    #pragma unroll
    for (int i = 0; i < 48; ++i) acc[i] = 0.f;
    for (int it = 0; it < 2; ++it){
      const int ll = it*64 + lane;
      float xv[32];
      #pragma unroll
      for (int c2 = 0; c2 < 16; ++c2){
        float2 t = xs[ll*17 + c2];
        xv[2*c2] = t.x; xv[2*c2+1] = t.y;
      }
      float qq[8], kk[8];
      #pragma unroll
      for (int r = 0; r < 8; ++r){ qq[r] = 0.f; kk[r] = 0.f; }
      #pragma unroll
      for (int c = 0; c < 32; ++c){
        #pragma unroll
        for (int r = 0; r < 8; ++r){
          qq[r] = fmaf(Wq[r*32 + c], xv[c], qq[r]);
          kk[r] = fmaf(Wk[r*32 + c], xv[c], kk[r]);
        }
      }
      #pragma unroll
      for (int hh = 0; hh < 2; ++hh){
        const float* q = qq + hh*4;
        const float* k = kk + hh*4;
        const int base = hh*24;
        #pragma unroll
        for (int d = 0; d < 4; ++d){
          #pragma unroll
          for (int e = 0; e < 4; ++e)
            acc[base + d*4 + e] = fmaf(q[d], k[e], acc[base + d*4 + e]);
        }
        #pragma unroll
        for (int d = 0; d < 4; ++d) acc[base + 16 + d] = fmaf(q[d], q[d], acc[base + 16 + d]);
        #pragma unroll
        for (int e = 0; e < 4; ++e) acc[base + 20 + e] = fmaf(k[e], k[e], acc[base + 20 + e]);
      }
    }
    float* dst = xa_sums + b*192 + wave*48;
    int ch;
    float s0 = bfly32<false>(acc, lane, &ch);
    if (lane < 32) atomicAdd(dst + ch, s0);
    int ch2;
    float s1 = bfly16_sum(acc + 32, lane, &ch2);
    if (lane < 16) atomicAdd(dst + 32 + ch2, s1);
  }
}

// ---------- K2: finalize, r6 structure (round-11) ----------
// Best measured finalize form: r6's grid(50,BN) x 256t separate LA/XA block
// populations (<=135.5us — never entered r6 top-5). r7 (512t two-tile,
// 142us), r8 (serial, 179), r9/r10 (balanced-half, 184, VGPR 128-union)
// all worse. One delta vs r6: XA blocks embed the M2 fold (attn_s by
// tid<32 -> tmpv by all 256 -> M2s by all 256, 3 barriers, aliased on
// vsh) keeping k_fold dispatch + M2 round-trip eliminated. LA blocks are
// the exact r6 body. Per-block paths disjoint -> regalloc should stay in
// the ~64-84 regime (r10's 128 was an intra-block union).
__global__ __launch_bounds__(256) void k_finalize2(const float* __restrict__ rgb,
    const float* __restrict__ freq, const float* __restrict__ Wqkv,
    const float* __restrict__ la_attn, const float* __restrict__ dconv_w,
    const float* __restrict__ Wp, const float* __restrict__ bp,
    const float* __restrict__ Wxa, const float* __restrict__ xtemp,
    const float* __restrict__ xWp, const float* __restrict__ xbp,
    const float* __restrict__ xa_sums,
    float* __restrict__ f1, float* __restrict__ sum1, unsigned* __restrict__ max1e,
    float* __restrict__ f2, float* __restrict__ sum2, unsigned* __restrict__ max2e){
  __shared__ unsigned vsh[264*17];     // 17.95 KB; XA blocks alias fold scratch
  const bool isXA = blockIdx.x >= 25;
  const int b = blockIdx.y, tid = threadIdx.x;
  const int bxt = isXA ? (int)blockIdx.x - 25 : (int)blockIdx.x;
  const int l0 = bxt*256;
  const int l = l0 + tid, lane = tid & 63;
  if (!isXA){
    // ======== LA block: exact r6 body ========
    const float* xg = rgb + (size_t)b*CL;
    float x[32];
    #pragma unroll
    for (int c = 0; c < 32; ++c) x[c] = xg[c*LN + l];
    {
      float v[32];
      #pragma unroll
      for (int r = 0; r < 32; ++r) v[r] = 0.f;
      const float* Wv = Wqkv + 64*32;
      #pragma unroll
      for (int c = 0; c < 32; ++c){
        #pragma unroll
        for (int r = 0; r < 32; ++r) v[r] = fmaf(Wv[r*32 + c], x[c], v[r]);
      }
      #pragma unroll
      for (int c2 = 0; c2 < 16; ++c2)
        vsh[(tid+4)*17 + c2] = pk_bf16(v[2*c2], v[2*c2+1]);
    }
    if (tid < 128){
      const int p = tid >> 4, c2 = tid & 15;
      const int hl  = (p < 4) ? (l0 - 4 + p) : (l0 + 252 + p);
      const int pos = (p < 4) ? p : (256 + p);
      float2 vh = make_float2(0.f, 0.f);
      if (hl >= 0 && hl < LN){
        const float* W0 = Wqkv + (64 + 2*c2)*32;
        #pragma unroll 8
        for (int cc = 0; cc < 32; ++cc){
          float xv = xg[cc*LN + hl];
          vh.x = fmaf(W0[cc],      xv, vh.x);
          vh.y = fmaf(W0[32 + cc], xv, vh.y);
        }
      }
      vsh[pos*17 + c2] = pk_bf16(vh.x, vh.y);
    }
    __syncthreads();
    float y[32];
    #pragma unroll
    for (int h = 0; h < 8; ++h){
      float q0 = 0.f, q1 = 0.f, q2 = 0.f, q3 = 0.f;
      const float* Wq = Wqkv + h*4*32;
      #pragma unroll
      for (int c = 0; c < 32; ++c){
        q0 = fmaf(Wq[c],      x[c], q0);
        q1 = fmaf(Wq[32 + c], x[c], q1);
        q2 = fmaf(Wq[64 + c], x[c], q2);
        q3 = fmaf(Wq[96 + c], x[c], q3);
      }
      const float rnq = rsqrtf(q0*q0 + q1*q1 + q2*q2 + q3*q3);
      q0 *= rnq; q1 *= rnq; q2 *= rnq; q3 *= rnq;
      const float* at = la_attn + b*128 + h*16;   // uniform -> s_load
      const float2 v01 = upk_bf16(vsh[(tid+4)*17 + h*2]);
      const float2 v23 = upk_bf16(vsh[(tid+4)*17 + h*2 + 1]);
      const float vo[4] = {v01.x, v01.y, v23.x, v23.y};
      float o[4]; float ss = 0.f;
      #pragma unroll
      for (int e = 0; e < 4; ++e){
        float tt = 0.f;
        tt = fmaf(q0, at[e],      tt);
        tt = fmaf(q1, at[4 + e],  tt);
        tt = fmaf(q2, at[8 + e],  tt);
        tt = fmaf(q3, at[12 + e], tt);
        o[e] = fmaf(0.31830988618379067f, tt, 0.5f*vo[e]);
        ss = fmaf(o[e], o[e], ss);
      }
      const float rno = rsqrtf(ss);
      float dc[4] = {0.f, 0.f, 0.f, 0.f};
      #pragma unroll
      for (int j = 0; j < 9; ++j){
        const float w = dconv_w[h*9 + j];
        const float2 p0 = upk_bf16(vsh[(tid + j)*17 + h*2]);
        const float2 p1 = upk_bf16(vsh[(tid + j)*17 + h*2 + 1]);
        dc[0] = fmaf(w, p0.x, dc[0]);
        dc[1] = fmaf(w, p0.y, dc[1]);
        dc[2] = fmaf(w, p1.x, dc[2]);
        dc[3] = fmaf(w, p1.y, dc[3]);
      }
      #pragma unroll
      for (int e = 0; e < 4; ++e) y[h*4 + e] = fmaf(o[e], rno, dc[e]);
    }
    float vals[32];
    float* f1p = f1 + (size_t)b*CL + l;
    #pragma unroll
    for (int r = 0; r < 32; ++r){
      float val = bp[r];
      #pragma unroll
      for (int c = 0; c < 32; ++c) val = fmaf(Wp[r*32 + c], y[c], val);
      f1p[r*LN] = val;
      vals[r] = val;
    }
    int ch;
    float s = bfly32<false>(vals, lane, &ch);
    float m = bfly32<true >(vals, lane, &ch);
    if (lane < 32){
      atomicAdd(&sum1[b*32 + ch], s);
      atomicMax(&max1e[b*32 + ch], fenc(m));
    }
  } else {
    // ======== XA block: embedded fold (3 barriers) + apply ========
    float* attn_s = (float*)vsh;          // 128
    float* tmpv_s = ((float*)vsh) + 128;  // 1024
    float* M2s    = ((float*)vsh) + 1152; // 1024  (total 8.6 KB of 17.95)
    const float* xf = freq + (size_t)b*CL;
    float x[32];
    #pragma unroll
    for (int c = 0; c < 32; ++c) x[c] = xf[c*LN + l];
    if (tid < 32){
      const int h = tid >> 2, d = tid & 3;
      const float* xss = xa_sums + b*192 + h*24;
      const float tmp = xtemp[h];
      const float nq = fmaxf(sqrtf(xss[16 + d]), 1e-12f);
      float lg[4]; float m = -1e30f;
      #pragma unroll
      for (int e = 0; e < 4; ++e){
        float nk = fmaxf(sqrtf(xss[20 + e]), 1e-12f);
        lg[e] = xss[d*4 + e] * tmp / (nq*nk);
        m = fmaxf(m, lg[e]);
      }
      float Z = 0.f;
      #pragma unroll
      for (int e = 0; e < 4; ++e){ lg[e] = __expf(lg[e] - m); Z += lg[e]; }
      float iZ = 1.f/Z;
      #pragma unroll
      for (int e = 0; e < 4; ++e) attn_s[h*16 + d*4 + e] = lg[e]*iZ;
    }
    __syncthreads();
    {
      const float* Wv = Wxa + 64*32;
      #pragma unroll
      for (int i = 0; i < 4; ++i){
        const int idx = tid*4 + i;
        const int k = idx >> 5, c = idx & 31;
        const int h = k >> 2, d = k & 3;
        float s = 0.f;
        #pragma unroll
        for (int e = 0; e < 4; ++e)
          s = fmaf(attn_s[h*16 + d*4 + e], Wv[(h*4 + e)*32 + c], s);
        tmpv_s[k*32 + c] = s;
      }
    }
    __syncthreads();
    {
      #pragma unroll
      for (int i = 0; i < 4; ++i){
        const int idx = tid*4 + i;
        const int r = idx >> 5, c = idx & 31;
        float s = 0.f;
        #pragma unroll
        for (int k = 0; k < 32; ++k)
          s = fmaf(xWp[r*32 + k], tmpv_s[k*32 + c], s);
        M2s[r*32 + c] = s;
      }
    }
    __syncthreads();
    float vals[32];
    #pragma unroll
    for (int r = 0; r < 32; ++r) vals[r] = xbp[r];
    #pragma unroll
    for (int c = 0; c < 32; ++c){
      #pragma unroll
      for (int r = 0; r < 32; ++r) vals[r] = fmaf(M2s[r*32 + c], x[c], vals[r]);
    }
    float* f2p = f2 + (size_t)b*CL + l;
    #pragma unroll
    for (int r = 0; r < 32; ++r) f2p[r*LN] = vals[r];
    int ch;
    float s = bfly32<false>(vals, lane, &ch);
    float m = bfly32<true >(vals, lane, &ch);
    if (lane < 32){
      atomicAdd(&sum2[b*32 + ch], s);
      atomicMax(&max2e[b*32 + ch], fenc(m));
    }
  }
}

// ---------- K6: mixing + pooling, with k_vec embedded (unchanged r7) ----------
__global__ __launch_bounds__(256) void k_mix(const float* __restrict__ f1,
    const float* __restrict__ f2,
    const float* __restrict__ sum1, const unsigned* __restrict__ max1e,
    const float* __restrict__ sum2, const unsigned* __restrict__ max2e,
    const float* __restrict__ a1w, const float* __restrict__ a1b,
    const float* __restrict__ m1w, const float* __restrict__ m1b,
    const float* __restrict__ a2w, const float* __restrict__ a2b,
    const float* __restrict__ m2w, const float* __restrict__ m2b,
    const float* __restrict__ a11w, const float* __restrict__ a11b,
    const float* __restrict__ m11w, const float* __restrict__ m11b,
    const float* __restrict__ a22w, const float* __restrict__ a22b,
    const float* __restrict__ m22w, const float* __restrict__ m22b,
    float* __restrict__ pooled1, float* __restrict__ pooled2){
  __shared__ float avg1[32], mx1[32], avg2[32], mx2[32];
  __shared__ float h_a1[16], h_m1[16], h_a2[16], h_m2[16];
  __shared__ float a1v[32], a2v[32];
  __shared__ float w1s[1024], w2s[1024];
  const int b = blockIdx.y, tid = threadIdx.x;
  const int l = blockIdx.x*256 + tid;
  if (tid < 32){
    avg1[tid] = sum1[b*32 + tid] * (1.f/6400.f);
    mx1[tid]  = fdec(max1e[b*32 + tid]);
    avg2[tid] = sum2[b*32 + tid] * (1.f/6400.f);
    mx2[tid]  = fdec(max2e[b*32 + tid]);
  }
  __syncthreads();
  if (tid < 16){
    float s1 = a1b[tid], s2 = m1b[tid], s3 = a2b[tid], s4 = m2b[tid];
    for (int c = 0; c < 32; ++c){
      s1 = fmaf(avg1[c], a1w[tid*32 + c], s1);
      s2 = fmaf(mx1[c],  m1w[tid*32 + c], s2);
      s3 = fmaf(avg2[c], a2w[tid*32 + c], s3);
      s4 = fmaf(mx2[c],  m2w[tid*32 + c], s4);
    }
    h_a1[tid] = fmaxf(s1, 0.f); h_m1[tid] = fmaxf(s2, 0.f);
    h_a2[tid] = fmaxf(s3, 0.f); h_m2[tid] = fmaxf(s4, 0.f);
  }
  __syncthreads();
  if (tid < 32){
    float v1 = a11b[tid] + m11b[tid];
    float v2 = a22b[tid] + m22b[tid];
    for (int k = 0; k < 16; ++k){
      v1 += h_a1[k]*a11w[tid*16 + k] + h_m1[k]*m11w[tid*16 + k];
      v2 += h_a2[k]*a22w[tid*16 + k] + h_m2[k]*m22w[tid*16 + k];
    }
    a1v[tid] = v1; a2v[tid] = v2;
  }
  __syncthreads();
  if (tid < 32){
    float s = a1v[tid], m = -1e30f;
    for (int d = 0; d < 32; ++d) m = fmaxf(m, s*a2v[d]);
    float Z = 0.f;
    for (int d = 0; d < 32; ++d) Z += __expf(s*a2v[d] - m);
    float iZ = 1.f/Z;
    for (int d = 0; d < 32; ++d) w1s[tid*32 + d] = __expf(s*a2v[d] - m)*iZ;
    float s2 = a2v[tid]; m = -1e30f;
    for (int d = 0; d < 32; ++d) m = fmaxf(m, s2*a1v[d]);
    Z = 0.f;
    for (int d = 0; d < 32; ++d) Z += __expf(s2*a1v[d] - m);
    iZ = 1.f/Z;
    for (int d = 0; d < 32; ++d) w2s[tid*32 + d] = __expf(s2*a1v[d] - m)*iZ;
  }
  __syncthreads();
  float fv[32], av[32];
  {
    const float* f1p = f1 + (size_t)b*CL + l;
    #pragma unroll
    for (int d = 0; d < 32; ++d) fv[d] = f1p[d*LN];
    #pragma unroll
    for (int c = 0; c < 32; ++c) av[c] = 0.f;
    #pragma unroll
    for (int d = 0; d < 32; ++d){
      #pragma unroll
      for (int c = 0; c < 32; ++c) av[c] = fmaf(w1s[c*32 + d], fv[d], av[c]);
    }
    float s = 0.f, m = -1e30f;
    #pragma unroll
    for (int c = 0; c < 32; ++c){ s += av[c]; m = fmaxf(m, av[c]); }
    pooled1[(size_t)b*2*LN + l]      = s*(1.f/32.f);
    pooled1[(size_t)b*2*LN + LN + l] = m;
  }
  {
    const float* f2p = f2 + (size_t)b*CL + l;
    #pragma unroll
    for (int d = 0; d < 32; ++d) fv[d] = f2p[d*LN];
    #pragma unroll
    for (int c = 0; c < 32; ++c) av[c] = 0.f;
    #pragma unroll
    for (int d = 0; d < 32; ++d){
      #pragma unroll
      for (int c = 0; c < 32; ++c) av[c] = fmaf(w2s[c*32 + d], fv[d], av[c]);
    }
    float s = 0.f, m = -1e30f;
    #pragma unroll
    for (int c = 0; c < 32; ++c){ s += av[c]; m = fmaxf(m, av[c]); }
    pooled2[(size_t)b*2*LN + l]      = s*(1.f/32.f);
    pooled2[(size_t)b*2*LN + LN + l] = m;
  }
}

// ---------- K7: gate, 1024 threads (validated r10: saved ~39us vs 256t) ----------
__global__ __launch_bounds__(1024) void k_gate(const float* __restrict__ pooled1,
    const float* __restrict__ pooled2, const float* __restrict__ c1w,
    const float* __restrict__ c1b, const float* __restrict__ c2w,
    const float* __restrict__ c2b, float* __restrict__ g1, float* __restrict__ g2){
  __shared__ float y1s[6400];
  __shared__ float red[32];
  const int b = blockIdx.y, t = blockIdx.x, tid = threadIdx.x;
  const float* src = (t == 0 ? pooled1 : pooled2) + (size_t)b*2*LN;
  float* dst = (t == 0 ? g1 : g2) + (size_t)b*LN;
  for (int i = tid; i < 6400; i += 1024){
    const int yy = i/80, xx = i - yy*80;
    float a = c1b[0];
    #pragma unroll
    for (int ky = 0; ky < 3; ++ky){
      const int y2 = yy + ky - 1;
      if (y2 < 0 || y2 >= 80) continue;
      #pragma unroll
      for (int kx = 0; kx < 3; ++kx){
        const int x2 = xx + kx - 1;
        if (x2 < 0 || x2 >= 80) continue;
        const int j = y2*80 + x2;
        a = fmaf(src[j],        c1w[ky*3 + kx],     a);
        a = fmaf(src[6400 + j], c1w[9 + ky*3 + kx], a);
      }
    }
    y1s[i] = fmaxf(a, 0.f);
  }
  __syncthreads();
  float y2r[7]; float lmax = -1e30f;
  #pragma unroll
  for (int ii = 0; ii < 7; ++ii){
    const int i = tid + ii*1024;
    if (i < 6400){
      const int yy = i/80, xx = i - yy*80;
      float a = c2b[0];
      #pragma unroll
      for (int ky = 0; ky < 3; ++ky){
        const int y2 = yy + ky - 1;
        if (y2 < 0 || y2 >= 80) continue;
        #pragma unroll
        for (int kx = 0; kx < 3; ++kx){
          const int x2 = xx + kx - 1;
          if (x2 < 0 || x2 >= 80) continue;
          a = fmaf(y1s[y2*80 + x2], c2w[ky*3 + kx], a);
        }
      }
      y2r[ii] = a; lmax = fmaxf(lmax, a);
    } else y2r[ii] = -1e30f;
  }
  #pragma unroll
  for (int off = 32; off >= 1; off >>= 1) lmax = fmaxf(lmax, __shfl_xor(lmax, off, 64));
  if ((tid & 63) == 0) red[tid >> 6] = lmax;
  __syncthreads();
  float bmax = red[0];
  #pragma unroll
  for (int i = 1; i < 16; ++i) bmax = fmaxf(bmax, red[i]);
  float lsum = 0.f;
  #pragma unroll
  for (int ii = 0; ii < 7; ++ii){
    const int i = tid + ii*1024;
    if (i < 6400){
      float e = __expf(y2r[ii] - bmax);
      y2r[ii] = e; lsum += e;
    }
  }
  #pragma unroll
  for (int off = 32; off >= 1; off >>= 1) lsum += __shfl_xor(lsum, off, 64);
  if ((tid & 63) == 0) red[16 + (tid >> 6)] = lsum;
  __syncthreads();
  float tsum = 0.f;
  #pragma unroll
  for (int i = 0; i < 16; ++i) tsum += red[16 + i];
  const float inv = 1.f/tsum;
  #pragma unroll
  for (int ii = 0; ii < 7; ++ii){
    const int i = tid + ii*1024;
    if (i < 6400) dst[i] = y2r[ii]*inv;
  }
}

// ---------- K8: out = f1*(1+g1) + f2*(1+g2) ----------
__global__ __launch_bounds__(256) void k_final(const float* __restrict__ f1,
    const float* __restrict__ f2, const float* __restrict__ g1,
    const float* __restrict__ g2, float* __restrict__ out){
  const int i = blockIdx.x*256 + threadIdx.x;
  const int flat = i*4;
  const int b = flat / CL;
  const int rem = flat - b*CL;
  const int l = rem % LN;
  const float4 a  = *(const float4*)(f1 + flat);
  const float4 c  = *(const float4*)(f2 + flat);
  const float4 ga = *(const float4*)(g1 + b*LN + l);
  const float4 gc = *(const float4*)(g2 + b*LN + l);
  float4 o;
  o.x = fmaf(a.x, ga.x, a.x) + fmaf(c.x, gc.x, c.x);
  o.y = fmaf(a.y, ga.y, a.y) + fmaf(c.y, gc.y, c.y);
  o.z = fmaf(a.z, ga.z, a.z) + fmaf(c.z, gc.z, c.z);
  o.w = fmaf(a.w, ga.w, a.w) + fmaf(c.w, gc.w, c.w);
  *(float4*)(out + flat) = o;
}

// ---------- host ----------
extern "C" void kernel_launch(void* const* d_in, const int* in_sizes, int n_in,
                              void* d_out, int out_size, void* d_ws, size_t ws_size,
                              hipStream_t stream){
  const float* rgb     = (const float*)d_in[0];
  const float* freq    = (const float*)d_in[1];
  const float* la_qkv  = (const float*)d_in[2];
  const float* la_pw   = (const float*)d_in[3];
  const float* la_pb   = (const float*)d_in[4];
  const float* la_dw   = (const float*)d_in[5];
  const float* xa_qkv  = (const float*)d_in[6];
  const float* xa_temp = (const float*)d_in[7];
  const float* xa_pw   = (const float*)d_in[8];
  const float* xa_pb   = (const float*)d_in[9];
  const float* c1w     = (const float*)d_in[10];
  const float* c1b     = (const float*)d_in[11];
  const float* c2w     = (const float*)d_in[12];
  const float* c2b     = (const float*)d_in[13];

  float* ws = (float*)d_ws;
  size_t o = 0;
  float* f1      = ws + o; o += (size_t)BN*CL;
  float* f2      = ws + o; o += (size_t)BN*CL;
  float* la_attn = ws + o; o += BN*128;
  float* xa_sums = ws + o; o += BN*192;
  float* sum1    = ws + o; o += BN*32;
  unsigned* max1e = (unsigned*)(ws + o); o += BN*32;
  float* sum2    = ws + o; o += BN*32;
  unsigned* max2e = (unsigned*)(ws + o); o += BN*32;
  float* pooled1 = ws + o; o += (size_t)BN*2*LN;
  float* pooled2 = ws + o; o += (size_t)BN*2*LN;
  float* g1      = ws + o; o += (size_t)BN*LN;
  float* g2      = ws + o; o += (size_t)BN*LN;

  // zero the atomically-accumulated regions (la_attn .. max2e, contiguous)
  const size_t nz = (size_t)BN*128 + BN*192 + (size_t)BN*32*4;
  hipMemsetAsync(la_attn, 0, nz*sizeof(float), stream);

  k_reduce2  <<<dim3(50, BN), 512, 0, stream>>>(rgb, freq, la_qkv, xa_qkv, la_attn, xa_sums);
  k_finalize2<<<dim3(50, BN), 256, 0, stream>>>(rgb, freq, la_qkv, la_attn, la_dw,
                                                la_pw, la_pb,
                                                xa_qkv, xa_temp, xa_pw, xa_pb, xa_sums,
                                                f1, sum1, max1e, f2, sum2, max2e);
  k_mix  <<<dim3(25, BN), 256, 0, stream>>>(f1, f2, sum1, max1e, sum2, max2e,
      (const float*)d_in[14], (const float*)d_in[15], (const float*)d_in[16], (const float*)d_in[17],
      (const float*)d_in[18], (const float*)d_in[19], (const float*)d_in[20], (const float*)d_in[21],
      (const float*)d_in[22], (const float*)d_in[23], (const float*)d_in[24], (const float*)d_in[25],
      (const float*)d_in[26], (const float*)d_in[27], (const float*)d_in[28], (const float*)d_in[29],
      pooled1, pooled2);
  k_gate <<<dim3(2, BN), 1024, 0, stream>>>(pooled1, pooled2, c1w, c1b, c2w, c2b, g1, g2);
  k_final<<<12800, 256, 0, stream>>>(f1, f2, g1, g2, (float*)d_out);
}

// Round 12
// 491.226 us; speedup vs baseline: 1.1899x; 1.1899x over previous
//
#include <hip/hip_runtime.h>

#define BN 64
#define CN 32
#define HEADSN 8
#define HDN 4
#define LN 6400
#define CL (CN*LN)   // 204800

// ---------- helpers ----------

__device__ __forceinline__ unsigned fenc(float f){
  unsigned u = __float_as_uint(f);
  return (u & 0x80000000u) ? ~u : (u | 0x80000000u);
}
__device__ __forceinline__ float fdec(unsigned u){
  unsigned v = (u & 0x80000000u) ? (u & 0x7FFFFFFFu) : ~u;
  return __uint_as_float(v);
}

// pack two f32 -> 2x bf16 (RNE) in one u32 ; unpack back to two f32
__device__ __forceinline__ unsigned pk_bf16(float a, float b){
  unsigned ua = __float_as_uint(a), ub = __float_as_uint(b);
  ua = (ua + 0x7fffu + ((ua >> 16) & 1u)) >> 16;
  ub = (ub + 0x7fffu + ((ub >> 16) & 1u)) >> 16;
  return ua | (ub << 16);
}
__device__ __forceinline__ float2 upk_bf16(unsigned u){
  return make_float2(__uint_as_float(u << 16), __uint_as_float(u & 0xffff0000u));
}

// Butterfly-reduce 32 per-thread values across the 64 lanes of a wave.
template<bool MAXOP>
__device__ __forceinline__ float bfly32(const float* in, int lane, int* chOut){
  const bool h0 = (lane & 1)  != 0, h1 = (lane & 2)  != 0, h2 = (lane & 4) != 0,
             h3 = (lane & 8)  != 0, h4 = (lane & 16) != 0;
  float a[16];
  #pragma unroll
  for (int i = 0; i < 16; ++i){
    float send = h0 ? in[i] : in[i+16];
    float keep = h0 ? in[i+16] : in[i];
    float recv = __shfl_xor(send, 1, 64);
    a[i] = MAXOP ? fmaxf(keep, recv) : keep + recv;
  }
  float b[8];
  #pragma unroll
  for (int i = 0; i < 8; ++i){
    float send = h1 ? a[i] : a[i+8];
    float keep = h1 ? a[i+8] : a[i];
    float recv = __shfl_xor(send, 2, 64);
    b[i] = MAXOP ? fmaxf(keep, recv) : keep + recv;
  }
  float c[4];
  #pragma unroll
  for (int i = 0; i < 4; ++i){
    float send = h2 ? b[i] : b[i+4];
    float keep = h2 ? b[i+4] : b[i];
    float recv = __shfl_xor(send, 4, 64);
    c[i] = MAXOP ? fmaxf(keep, recv) : keep + recv;
  }
  float d[2];
  #pragma unroll
  for (int i = 0; i < 2; ++i){
    float send = h3 ? c[i] : c[i+2];
    float keep = h3 ? c[i+2] : c[i];
    float recv = __shfl_xor(send, 8, 64);
    d[i] = MAXOP ? fmaxf(keep, recv) : keep + recv;
  }
  float e;
  {
    float send = h4 ? d[0] : d[1];
    float keep = h4 ? d[1] : d[0];
    float recv = __shfl_xor(send, 16, 64);
    e = MAXOP ? fmaxf(keep, recv) : keep + recv;
  }
  {
    float recv = __shfl_xor(e, 32, 64);
    e = MAXOP ? fmaxf(e, recv) : e + recv;
  }
  *chOut = (h0?16:0)|(h1?8:0)|(h2?4:0)|(h3?2:0)|(h4?1:0);
  return e;
}

__device__ __forceinline__ float bfly16_sum(const float* in, int lane, int* chOut){
  const bool h0 = (lane & 1) != 0, h1 = (lane & 2) != 0, h2 = (lane & 4) != 0,
             h3 = (lane & 8) != 0;
  float a[8];
  #pragma unroll
  for (int i = 0; i < 8; ++i){
    float send = h0 ? in[i] : in[i+8];
    float keep = h0 ? in[i+8] : in[i];
    float recv = __shfl_xor(send, 1, 64);
    a[i] = keep + recv;
  }
  float b[4];
  #pragma unroll
  for (int i = 0; i < 4; ++i){
    float send = h1 ? a[i] : a[i+4];
    float keep = h1 ? a[i+4] : a[i];
    float recv = __shfl_xor(send, 2, 64);
    b[i] = keep + recv;
  }
  float c[2];
  #pragma unroll
  for (int i = 0; i < 2; ++i){
    float send = h2 ? b[i] : b[i+2];
    float keep = h2 ? b[i+2] : b[i];
    float recv = __shfl_xor(send, 4, 64);
    c[i] = keep + recv;
  }
  float e;
  {
    float send = h3 ? c[0] : c[1];
    float keep = h3 ? c[1] : c[0];
    float recv = __shfl_xor(send, 8, 64);
    e = keep + recv;
  }
  e += __shfl_xor(e, 16, 64);
  e += __shfl_xor(e, 32, 64);
  *chOut = (h0?8:0)|(h1?4:0)|(h2?2:0)|(h3?1:0);
  return e;
}

// ---------- K1: merged LA+XCA reduce, 512-thread blocks (r7, measured) ----------
__global__ __launch_bounds__(512) void k_reduce2(const float* __restrict__ rgb,
    const float* __restrict__ freq, const float* __restrict__ Wla,
    const float* __restrict__ Wxa, float* __restrict__ la_attn,
    float* __restrict__ xa_sums){
  __shared__ float2 xs2[2*128*17];     // 34.8 KB: two 128-px tiles
  const bool isXA = blockIdx.x >= 25;
  const int b = blockIdx.y, tid = threadIdx.x;
  const int half = tid >> 8;           // which tile
  const int wt = tid & 255;
  const int bxt = isXA ? (int)blockIdx.x - 25 : (int)blockIdx.x;
  const int l0 = (bxt*2 + half)*128;
  const float* xg = (isXA ? freq : rgb) + (size_t)b*CL + l0;
  float2* xs = xs2 + half*(128*17);
  // stage: 128 px x 16 channel-pairs per tile, 8 pairs per thread
  {
    const int px = wt & 127;
    const int c2b_ = (wt >> 7)*8;
    #pragma unroll
    for (int j = 0; j < 8; ++j){
      const int c2 = c2b_ + j;
      float e0 = xg[(2*c2)*LN + px];
      float e1 = xg[(2*c2+1)*LN + px];
      xs[px*17 + c2] = make_float2(e0, e1);
    }
  }
  __syncthreads();
  const int wave = __builtin_amdgcn_readfirstlane((tid >> 6) & 3);
  const int lane = tid & 63;
  if (!isXA){
    const float* Wk = Wla + (32 + wave*8)*32;
    const float* Wv = Wla + (64 + wave*8)*32;
    float acc[32];
    #pragma unroll
    for (int i = 0; i < 32; ++i) acc[i] = 0.f;
    for (int it = 0; it < 2; ++it){
      const int ll = it*64 + lane;
      float xv[32];
      #pragma unroll
      for (int c2 = 0; c2 < 16; ++c2){
        float2 t = xs[ll*17 + c2];
        xv[2*c2] = t.x; xv[2*c2+1] = t.y;
      }
      float kk[8], vv[8];
      #pragma unroll
      for (int r = 0; r < 8; ++r){ kk[r] = 0.f; vv[r] = 0.f; }
      #pragma unroll
      for (int c = 0; c < 32; ++c){
        #pragma unroll
        for (int r = 0; r < 8; ++r){
          kk[r] = fmaf(Wk[r*32 + c], xv[c], kk[r]);
          vv[r] = fmaf(Wv[r*32 + c], xv[c], vv[r]);
        }
      }
      #pragma unroll
      for (int hh = 0; hh < 2; ++hh){
        const float* k = kk + hh*4;
        const float* v = vv + hh*4;
        float rn = rsqrtf(k[0]*k[0] + k[1]*k[1] + k[2]*k[2] + k[3]*k[3]);
        #pragma unroll
        for (int d = 0; d < 4; ++d){
          float kn = k[d]*rn;
          #pragma unroll
          for (int e = 0; e < 4; ++e)
            acc[hh*16 + d*4 + e] = fmaf(kn, v[e], acc[hh*16 + d*4 + e]);
        }
      }
    }
    int ch;
    float s = bfly32<false>(acc, lane, &ch);
    if (lane < 32) atomicAdd(la_attn + b*128 + wave*32 + ch, s);
  } else {
    const float* Wq = Wxa + (0  + wave*8)*32;
    const float* Wk = Wxa + (32 + wave*8)*32;
    float acc[48];
    #pragma unroll
    for (int i = 0; i < 48; ++i) acc[i] = 0.f;
    for (int it = 0; it < 2; ++it){
      const int ll = it*64 + lane;
      float xv[32];
      #pragma unroll
      for (int c2 = 0; c2 < 16; ++c2){
        float2 t = xs[ll*17 + c2];
        xv[2*c2] = t.x; xv[2*c2+1] = t.y;
      }
      float qq[8], kk[8];
      #pragma unroll
      for (int r = 0; r < 8; ++r){ qq[r] = 0.f; kk[r] = 0.f; }
      #pragma unroll
      for (int c = 0; c < 32; ++c){
        #pragma unroll
        for (int r = 0; r < 8; ++r){
          qq[r] = fmaf(Wq[r*32 + c], xv[c], qq[r]);
          kk[r] = fmaf(Wk[r*32 + c], xv[c], kk[r]);
        }
      }
      #pragma unroll
      for (int hh = 0; hh < 2; ++hh){
        const float* q = qq + hh*4;
        const float* k = kk + hh*4;
        const int base = hh*24;
        #pragma unroll
        for (int d = 0; d < 4; ++d){
          #pragma unroll
          for (int e = 0; e < 4; ++e)
            acc[base + d*4 + e] = fmaf(q[d], k[e], acc[base + d*4 + e]);
        }
        #pragma unroll
        for (int d = 0; d < 4; ++d) acc[base + 16 + d] = fmaf(q[d], q[d], acc[base + 16 + d]);
        #pragma unroll
        for (int e = 0; e < 4; ++e) acc[base + 20 + e] = fmaf(k[e], k[e], acc[base + 20 + e]);
      }
    }
    float* dst = xa_sums + b*192 + wave*48;
    int ch;
    float s0 = bfly32<false>(acc, lane, &ch);
    if (lane < 32) atomicAdd(dst + ch, s0);
    int ch2;
    float s1 = bfly16_sum(acc + 32, lane, &ch2);
    if (lane < 16) atomicAdd(dst + 32 + ch2, s1);
  }
}

// ---------- K2: merged LA+XCA finalize, 512t two-tile, fold embedded ----------
// EXACT r7 form: measured 142us @ VGPR 84, complete-pipeline-validated at
// 529.7us total. r8 (serial 256t: 179), r9/r10 (balanced-half: 184, VGPR
// 128), r11 (fold-embedded 256t: 178, VGPR 124) all worse — the r7 union
// of {two-tile LA} vs {fold+apply XA} is the allocator-friendliest split
// found in 5 attempts. Do not restructure again without new counter evidence.
__global__ __launch_bounds__(512) void k_finalize2(const float* __restrict__ rgb,
    const float* __restrict__ freq, const float* __restrict__ Wqkv,
    const float* __restrict__ la_attn, const float* __restrict__ dconv_w,
    const float* __restrict__ Wp, const float* __restrict__ bp,
    const float* __restrict__ Wxa, const float* __restrict__ xtemp,
    const float* __restrict__ xWp, const float* __restrict__ xbp,
    const float* __restrict__ xa_sums,
    float* __restrict__ f1, float* __restrict__ sum1, unsigned* __restrict__ max1e,
    float* __restrict__ f2, float* __restrict__ sum2, unsigned* __restrict__ max2e){
  __shared__ unsigned vsh[2*264*17];   // 35.9 KB; XA blocks alias M2s/attn_s
  const bool isXA = blockIdx.x >= 13;
  const int b = blockIdx.y, tid = threadIdx.x;
  const int half = tid >> 8, t = tid & 255;
  const int bxt = isXA ? (int)blockIdx.x - 13 : (int)blockIdx.x;
  const int tile = bxt*2 + half;
  const bool valid = tile < 25;
  const int l0 = tile*256;
  const int l = l0 + t, lane = tid & 63;
  unsigned* vs = vsh + half*(264*17);
  if (!isXA){
    const float* xg = rgb + (size_t)b*CL;
    float x[32];
    if (valid){
      #pragma unroll
      for (int c = 0; c < 32; ++c) x[c] = xg[c*LN + l];
      // own v -> conv tile
      {
        float v[32];
        #pragma unroll
        for (int r = 0; r < 32; ++r) v[r] = 0.f;
        const float* Wv = Wqkv + 64*32;
        #pragma unroll
        for (int c = 0; c < 32; ++c){
          #pragma unroll
          for (int r = 0; r < 32; ++r) v[r] = fmaf(Wv[r*32 + c], x[c], v[r]);
        }
        #pragma unroll
        for (int c2 = 0; c2 < 16; ++c2)
          vs[(t+4)*17 + c2] = pk_bf16(v[2*c2], v[2*c2+1]);
      }
      // halo v: 8 pixels x 16 packed pairs, one (p,c2) per thread (t<128)
      if (t < 128){
        const int p = t >> 4, c2 = t & 15;
        const int hl  = (p < 4) ? (l0 - 4 + p) : (l0 + 252 + p);
        const int pos = (p < 4) ? p : (256 + p);
        float2 vh = make_float2(0.f, 0.f);
        if (hl >= 0 && hl < LN){
          const float* W0 = Wqkv + (64 + 2*c2)*32;
          #pragma unroll 8
          for (int cc = 0; cc < 32; ++cc){
            float xv = xg[cc*LN + hl];
            vh.x = fmaf(W0[cc],      xv, vh.x);
            vh.y = fmaf(W0[32 + cc], xv, vh.y);
          }
        }
        vs[pos*17 + c2] = pk_bf16(vh.x, vh.y);
      }
    }
    __syncthreads();
    if (valid){
      float y[32];
      #pragma unroll
      for (int h = 0; h < 8; ++h){
        float q0 = 0.f, q1 = 0.f, q2 = 0.f, q3 = 0.f;
        const float* Wq = Wqkv + h*4*32;
        #pragma unroll
        for (int c = 0; c < 32; ++c){
          q0 = fmaf(Wq[c],      x[c], q0);
          q1 = fmaf(Wq[32 + c], x[c], q1);
          q2 = fmaf(Wq[64 + c], x[c], q2);
          q3 = fmaf(Wq[96 + c], x[c], q3);
        }
        const float rnq = rsqrtf(q0*q0 + q1*q1 + q2*q2 + q3*q3);
        q0 *= rnq; q1 *= rnq; q2 *= rnq; q3 *= rnq;
        const float* at = la_attn + b*128 + h*16;   // uniform -> s_load
        const float2 v01 = upk_bf16(vs[(t+4)*17 + h*2]);
        const float2 v23 = upk_bf16(vs[(t+4)*17 + h*2 + 1]);
        const float vo[4] = {v01.x, v01.y, v23.x, v23.y};
        float o[4]; float ss = 0.f;
        #pragma unroll
        for (int e = 0; e < 4; ++e){
          float tt = 0.f;
          tt = fmaf(q0, at[e],      tt);
          tt = fmaf(q1, at[4 + e],  tt);
          tt = fmaf(q2, at[8 + e],  tt);
          tt = fmaf(q3, at[12 + e], tt);
          o[e] = fmaf(0.31830988618379067f, tt, 0.5f*vo[e]);
          ss = fmaf(o[e], o[e], ss);
        }
        const float rno = rsqrtf(ss);
        float dc[4] = {0.f, 0.f, 0.f, 0.f};
        #pragma unroll
        for (int j = 0; j < 9; ++j){
          const float w = dconv_w[h*9 + j];
          const float2 p0 = upk_bf16(vs[(t + j)*17 + h*2]);
          const float2 p1 = upk_bf16(vs[(t + j)*17 + h*2 + 1]);
          dc[0] = fmaf(w, p0.x, dc[0]);
          dc[1] = fmaf(w, p0.y, dc[1]);
          dc[2] = fmaf(w, p1.x, dc[2]);
          dc[3] = fmaf(w, p1.y, dc[3]);
        }
        #pragma unroll
        for (int e = 0; e < 4; ++e) y[h*4 + e] = fmaf(o[e], rno, dc[e]);
      }
      // projection + stats
      float vals[32];
      float* f1p = f1 + (size_t)b*CL + l;
      #pragma unroll
      for (int r = 0; r < 32; ++r){
        float val = bp[r];
        #pragma unroll
        for (int c = 0; c < 32; ++c) val = fmaf(Wp[r*32 + c], y[c], val);
        f1p[r*LN] = val;
        vals[r] = val;
      }
      int ch;
      float s = bfly32<false>(vals, lane, &ch);
      float m = bfly32<true >(vals, lane, &ch);
      if (lane < 32){
        atomicAdd(&sum1[b*32 + ch], s);
        atomicMax(&max1e[b*32 + ch], fenc(m));
      }
    }
  } else {
    // ---- XCA: fold M2[b] into LDS (old k_fold, same math), then apply
    float* M2s    = (float*)vsh;          // 1024 floats
    float* attn_s = ((float*)vsh) + 1024; // 128 floats
    if (tid < 32){
      const int h = tid >> 2, d = tid & 3;
      const float* xss = xa_sums + b*192 + h*24;
      const float tmp = xtemp[h];
      const float nq = fmaxf(sqrtf(xss[16 + d]), 1e-12f);
      float lg[4]; float m = -1e30f;
      #pragma unroll
      for (int e = 0; e < 4; ++e){
        float nk = fmaxf(sqrtf(xss[20 + e]), 1e-12f);
        lg[e] = xss[d*4 + e] * tmp / (nq*nk);
        m = fmaxf(m, lg[e]);
      }
      float Z = 0.f;
      #pragma unroll
      for (int e = 0; e < 4; ++e){ lg[e] = __expf(lg[e] - m); Z += lg[e]; }
      float iZ = 1.f/Z;
      #pragma unroll
      for (int e = 0; e < 4; ++e) attn_s[h*16 + d*4 + e] = lg[e]*iZ;
    }
    __syncthreads();
    if (tid < 32){
      const int c = tid;                    // column of M2
      const float* Wv = Wxa + 64*32;
      float tmpv[32];
      #pragma unroll
      for (int k = 0; k < 32; ++k){
        const int h = k >> 2, d = k & 3;
        float s = 0.f;
        #pragma unroll
        for (int e = 0; e < 4; ++e)
          s = fmaf(attn_s[h*16 + d*4 + e], Wv[(h*4 + e)*32 + c], s);
        tmpv[k] = s;
      }
      float out[32];
      #pragma unroll
      for (int r = 0; r < 32; ++r) out[r] = 0.f;
      #pragma unroll
      for (int k = 0; k < 32; ++k){
        #pragma unroll
        for (int r = 0; r < 32; ++r)
          out[r] = fmaf(xWp[r*32 + k], tmpv[k], out[r]);
      }
      #pragma unroll
      for (int r = 0; r < 32; ++r) M2s[r*32 + c] = out[r];
    }
    __syncthreads();
    if (valid){
      const float* xg = freq + (size_t)b*CL;
      float x[32];
      #pragma unroll
      for (int c = 0; c < 32; ++c) x[c] = xg[c*LN + l];
      float vals[32];
      #pragma unroll
      for (int r = 0; r < 32; ++r) vals[r] = xbp[r];
      #pragma unroll
      for (int c = 0; c < 32; ++c){
        #pragma unroll
        for (int r = 0; r < 32; ++r) vals[r] = fmaf(M2s[r*32 + c], x[c], vals[r]);
      }
      float* f2p = f2 + (size_t)b*CL + l;
      #pragma unroll
      for (int r = 0; r < 32; ++r) f2p[r*LN] = vals[r];
      int ch;
      float s = bfly32<false>(vals, lane, &ch);
      float m = bfly32<true >(vals, lane, &ch);
      if (lane < 32){
        atomicAdd(&sum2[b*32 + ch], s);
        atomicMax(&max2e[b*32 + ch], fenc(m));
      }
    }
  }
}

// ---------- K6: mixing + pooling, with k_vec embedded (r7, measured) ----------
__global__ __launch_bounds__(256) void k_mix(const float* __restrict__ f1,
    const float* __restrict__ f2,
    const float* __restrict__ sum1, const unsigned* __restrict__ max1e,
    const float* __restrict__ sum2, const unsigned* __restrict__ max2e,
    const float* __restrict__ a1w, const float* __restrict__ a1b,
    const float* __restrict__ m1w, const float* __restrict__ m1b,
    const float* __restrict__ a2w, const float* __restrict__ a2b,
    const float* __restrict__ m2w, const float* __restrict__ m2b,
    const float* __restrict__ a11w, const float* __restrict__ a11b,
    const float* __restrict__ m11w, const float* __restrict__ m11b,
    const float* __restrict__ a22w, const float* __restrict__ a22b,
    const float* __restrict__ m22w, const float* __restrict__ m22b,
    float* __restrict__ pooled1, float* __restrict__ pooled2){
  __shared__ float avg1[32], mx1[32], avg2[32], mx2[32];
  __shared__ float h_a1[16], h_m1[16], h_a2[16], h_m2[16];
  __shared__ float a1v[32], a2v[32];
  __shared__ float w1s[1024], w2s[1024];
  const int b = blockIdx.y, tid = threadIdx.x;
  const int l = blockIdx.x*256 + tid;
  if (tid < 32){
    avg1[tid] = sum1[b*32 + tid] * (1.f/6400.f);
    mx1[tid]  = fdec(max1e[b*32 + tid]);
    avg2[tid] = sum2[b*32 + tid] * (1.f/6400.f);
    mx2[tid]  = fdec(max2e[b*32 + tid]);
  }
  __syncthreads();
  if (tid < 16){
    float s1 = a1b[tid], s2 = m1b[tid], s3 = a2b[tid], s4 = m2b[tid];
    for (int c = 0; c < 32; ++c){
      s1 = fmaf(avg1[c], a1w[tid*32 + c], s1);
      s2 = fmaf(mx1[c],  m1w[tid*32 + c], s2);
      s3 = fmaf(avg2[c], a2w[tid*32 + c], s3);
      s4 = fmaf(mx2[c],  m2w[tid*32 + c], s4);
    }
    h_a1[tid] = fmaxf(s1, 0.f); h_m1[tid] = fmaxf(s2, 0.f);
    h_a2[tid] = fmaxf(s3, 0.f); h_m2[tid] = fmaxf(s4, 0.f);
  }
  __syncthreads();
  if (tid < 32){
    float v1 = a11b[tid] + m11b[tid];
    float v2 = a22b[tid] + m22b[tid];
    for (int k = 0; k < 16; ++k){
      v1 += h_a1[k]*a11w[tid*16 + k] + h_m1[k]*m11w[tid*16 + k];
      v2 += h_a2[k]*a22w[tid*16 + k] + h_m2[k]*m22w[tid*16 + k];
    }
    a1v[tid] = v1; a2v[tid] = v2;
  }
  __syncthreads();
  if (tid < 32){
    float s = a1v[tid], m = -1e30f;
    for (int d = 0; d < 32; ++d) m = fmaxf(m, s*a2v[d]);
    float Z = 0.f;
    for (int d = 0; d < 32; ++d) Z += __expf(s*a2v[d] - m);
    float iZ = 1.f/Z;
    for (int d = 0; d < 32; ++d) w1s[tid*32 + d] = __expf(s*a2v[d] - m)*iZ;
    float s2 = a2v[tid]; m = -1e30f;
    for (int d = 0; d < 32; ++d) m = fmaxf(m, s2*a1v[d]);
    Z = 0.f;
    for (int d = 0; d < 32; ++d) Z += __expf(s2*a1v[d] - m);
    iZ = 1.f/Z;
    for (int d = 0; d < 32; ++d) w2s[tid*32 + d] = __expf(s2*a1v[d] - m)*iZ;
  }
  __syncthreads();
  float fv[32], av[32];
  {
    const float* f1p = f1 + (size_t)b*CL + l;
    #pragma unroll
    for (int d = 0; d < 32; ++d) fv[d] = f1p[d*LN];
    #pragma unroll
    for (int c = 0; c < 32; ++c) av[c] = 0.f;
    #pragma unroll
    for (int d = 0; d < 32; ++d){
      #pragma unroll
      for (int c = 0; c < 32; ++c) av[c] = fmaf(w1s[c*32 + d], fv[d], av[c]);
    }
    float s = 0.f, m = -1e30f;
    #pragma unroll
    for (int c = 0; c < 32; ++c){ s += av[c]; m = fmaxf(m, av[c]); }
    pooled1[(size_t)b*2*LN + l]      = s*(1.f/32.f);
    pooled1[(size_t)b*2*LN + LN + l] = m;
  }
  {
    const float* f2p = f2 + (size_t)b*CL + l;
    #pragma unroll
    for (int d = 0; d < 32; ++d) fv[d] = f2p[d*LN];
    #pragma unroll
    for (int c = 0; c < 32; ++c) av[c] = 0.f;
    #pragma unroll
    for (int d = 0; d < 32; ++d){
      #pragma unroll
      for (int c = 0; c < 32; ++c) av[c] = fmaf(w2s[c*32 + d], fv[d], av[c]);
    }
    float s = 0.f, m = -1e30f;
    #pragma unroll
    for (int c = 0; c < 32; ++c){ s += av[c]; m = fmaxf(m, av[c]); }
    pooled2[(size_t)b*2*LN + l]      = s*(1.f/32.f);
    pooled2[(size_t)b*2*LN + LN + l] = m;
  }
}

// ---------- K7: gate, 1024 threads (validated r10: ~39us saving vs 256t) ----------
__global__ __launch_bounds__(1024) void k_gate(const float* __restrict__ pooled1,
    const float* __restrict__ pooled2, const float* __restrict__ c1w,
    const float* __restrict__ c1b, const float* __restrict__ c2w,
    const float* __restrict__ c2b, float* __restrict__ g1, float* __restrict__ g2){
  __shared__ float y1s[6400];
  __shared__ float red[32];
  const int b = blockIdx.y, t = blockIdx.x, tid = threadIdx.x;
  const float* src = (t == 0 ? pooled1 : pooled2) + (size_t)b*2*LN;
  float* dst = (t == 0 ? g1 : g2) + (size_t)b*LN;
  for (int i = tid; i < 6400; i += 1024){
    const int yy = i/80, xx = i - yy*80;
    float a = c1b[0];
    #pragma unroll
    for (int ky = 0; ky < 3; ++ky){
      const int y2 = yy + ky - 1;
      if (y2 < 0 || y2 >= 80) continue;
      #pragma unroll
      for (int kx = 0; kx < 3; ++kx){
        const int x2 = xx + kx - 1;
        if (x2 < 0 || x2 >= 80) continue;
        const int j = y2*80 + x2;
        a = fmaf(src[j],        c1w[ky*3 + kx],     a);
        a = fmaf(src[6400 + j], c1w[9 + ky*3 + kx], a);
      }
    }
    y1s[i] = fmaxf(a, 0.f);
  }
  __syncthreads();
  float y2r[7]; float lmax = -1e30f;
  #pragma unroll
  for (int ii = 0; ii < 7; ++ii){
    const int i = tid + ii*1024;
    if (i < 6400){
      const int yy = i/80, xx = i - yy*80;
      float a = c2b[0];
      #pragma unroll
      for (int ky = 0; ky < 3; ++ky){
        const int y2 = yy + ky - 1;
        if (y2 < 0 || y2 >= 80) continue;
        #pragma unroll
        for (int kx = 0; kx < 3; ++kx){
          const int x2 = xx + kx - 1;
          if (x2 < 0 || x2 >= 80) continue;
          a = fmaf(y1s[y2*80 + x2], c2w[ky*3 + kx], a);
        }
      }
      y2r[ii] = a; lmax = fmaxf(lmax, a);
    } else y2r[ii] = -1e30f;
  }
  #pragma unroll
  for (int off = 32; off >= 1; off >>= 1) lmax = fmaxf(lmax, __shfl_xor(lmax, off, 64));
  if ((tid & 63) == 0) red[tid >> 6] = lmax;
  __syncthreads();
  float bmax = red[0];
  #pragma unroll
  for (int i = 1; i < 16; ++i) bmax = fmaxf(bmax, red[i]);
  float lsum = 0.f;
  #pragma unroll
  for (int ii = 0; ii < 7; ++ii){
    const int i = tid + ii*1024;
    if (i < 6400){
      float e = __expf(y2r[ii] - bmax);
      y2r[ii] = e; lsum += e;
    }
  }
  #pragma unroll
  for (int off = 32; off >= 1; off >>= 1) lsum += __shfl_xor(lsum, off, 64);
  if ((tid & 63) == 0) red[16 + (tid >> 6)] = lsum;
  __syncthreads();
  float tsum = 0.f;
  #pragma unroll
  for (int i = 0; i < 16; ++i) tsum += red[16 + i];
  const float inv = 1.f/tsum;
  #pragma unroll
  for (int ii = 0; ii < 7; ++ii){
    const int i = tid + ii*1024;
    if (i < 6400) dst[i] = y2r[ii]*inv;
  }
}

// ---------- K8: out = f1*(1+g1) + f2*(1+g2) ----------
__global__ __launch_bounds__(256) void k_final(const float* __restrict__ f1,
    const float* __restrict__ f2, const float* __restrict__ g1,
    const float* __restrict__ g2, float* __restrict__ out){
  const int i = blockIdx.x*256 + threadIdx.x;
  const int flat = i*4;
  const int b = flat / CL;
  const int rem = flat - b*CL;
  const int l = rem % LN;
  const float4 a  = *(const float4*)(f1 + flat);
  const float4 c  = *(const float4*)(f2 + flat);
  const float4 ga = *(const float4*)(g1 + b*LN + l);
  const float4 gc = *(const float4*)(g2 + b*LN + l);
  float4 o;
  o.x = fmaf(a.x, ga.x, a.x) + fmaf(c.x, gc.x, c.x);
  o.y = fmaf(a.y, ga.y, a.y) + fmaf(c.y, gc.y, c.y);
  o.z = fmaf(a.z, ga.z, a.z) + fmaf(c.z, gc.z, c.z);
  o.w = fmaf(a.w, ga.w, a.w) + fmaf(c.w, gc.w, c.w);
  *(float4*)(out + flat) = o;
}

// ---------- host ----------
extern "C" void kernel_launch(void* const* d_in, const int* in_sizes, int n_in,
                              void* d_out, int out_size, void* d_ws, size_t ws_size,
                              hipStream_t stream){
  const float* rgb     = (const float*)d_in[0];
  const float* freq    = (const float*)d_in[1];
  const float* la_qkv  = (const float*)d_in[2];
  const float* la_pw   = (const float*)d_in[3];
  const float* la_pb   = (const float*)d_in[4];
  const float* la_dw   = (const float*)d_in[5];
  const float* xa_qkv  = (const float*)d_in[6];
  const float* xa_temp = (const float*)d_in[7];
  const float* xa_pw   = (const float*)d_in[8];
  const float* xa_pb   = (const float*)d_in[9];
  const float* c1w     = (const float*)d_in[10];
  const float* c1b     = (const float*)d_in[11];
  const float* c2w     = (const float*)d_in[12];
  const float* c2b     = (const float*)d_in[13];

  float* ws = (float*)d_ws;
  size_t o = 0;
  float* f1      = ws + o; o += (size_t)BN*CL;
  float* f2      = ws + o; o += (size_t)BN*CL;
  float* la_attn = ws + o; o += BN*128;
  float* xa_sums = ws + o; o += BN*192;
  float* sum1    = ws + o; o += BN*32;
  unsigned* max1e = (unsigned*)(ws + o); o += BN*32;
  float* sum2    = ws + o; o += BN*32;
  unsigned* max2e = (unsigned*)(ws + o); o += BN*32;
  float* pooled1 = ws + o; o += (size_t)BN*2*LN;
  float* pooled2 = ws + o; o += (size_t)BN*2*LN;
  float* g1      = ws + o; o += (size_t)BN*LN;
  float* g2      = ws + o; o += (size_t)BN*LN;

  // zero the atomically-accumulated regions (la_attn .. max2e, contiguous)
  const size_t nz = (size_t)BN*128 + BN*192 + (size_t)BN*32*4;
  hipMemsetAsync(la_attn, 0, nz*sizeof(float), stream);

  k_reduce2  <<<dim3(50, BN), 512, 0, stream>>>(rgb, freq, la_qkv, xa_qkv, la_attn, xa_sums);
  k_finalize2<<<dim3(26, BN), 512, 0, stream>>>(rgb, freq, la_qkv, la_attn, la_dw,
                                                la_pw, la_pb,
                                                xa_qkv, xa_temp, xa_pw, xa_pb, xa_sums,
                                                f1, sum1, max1e, f2, sum2, max2e);
  k_mix  <<<dim3(25, BN), 256, 0, stream>>>(f1, f2, sum1, max1e, sum2, max2e,
      (const float*)d_in[14], (const float*)d_in[15], (const float*)d_in[16], (const float*)d_in[17],
      (const float*)d_in[18], (const float*)d_in[19], (const float*)d_in[20], (const float*)d_in[21],
      (const float*)d_in[22], (const float*)d_in[23], (const float*)d_in[24], (const float*)d_in[25],
      (const float*)d_in[26], (const float*)d_in[27], (const float*)d_in[28], (const float*)d_in[29],
      pooled1, pooled2);
  k_gate <<<dim3(2, BN), 1024, 0, stream>>>(pooled1, pooled2, c1w, c1b, c2w, c2b, g1, g2);
  k_final<<<12800, 256, 0, stream>>>(f1, f2, g1, g2, (float*)d_out);
}